// Round 2
// baseline (1192.880 us; speedup 1.0000x reference)
//
#include <hip/hip_runtime.h>
#include <stdint.h>

#define NN 100000      // nodes
#define NE 1600000     // edges
#define INC 128        // in channels
#define HID 256        // hidden
#define MP  100032     // padded rows (64*1563)
#define MBLK 1563      // row blocks of 64
#define NBK 391        // dst buckets (dst>>8), 99999>>8 = 390
#define EPB 2048       // edges per bucket-fill block

typedef unsigned short u16;
typedef __attribute__((ext_vector_type(4))) float f32x4;
typedef __attribute__((ext_vector_type(8))) short s16x8;

static __device__ __forceinline__ float bf2f(u16 u){
  union { uint32_t i; float f; } v; v.i = ((uint32_t)u) << 16; return v.f;
}
static __device__ __forceinline__ u16 f2bf(float f){
  union { float f; uint32_t i; } v; v.f = f;
  uint32_t r = v.i + 0x7FFFu + ((v.i >> 16) & 1u);
  return (u16)(r >> 16);
}
static __device__ __forceinline__ void up8(uint4 o, float* v){
  v[0]=bf2f((u16)(o.x&0xffffu)); v[1]=bf2f((u16)(o.x>>16));
  v[2]=bf2f((u16)(o.y&0xffffu)); v[3]=bf2f((u16)(o.y>>16));
  v[4]=bf2f((u16)(o.z&0xffffu)); v[5]=bf2f((u16)(o.z>>16));
  v[6]=bf2f((u16)(o.w&0xffffu)); v[7]=bf2f((u16)(o.w>>16));
}
static __device__ __forceinline__ uint4 pk8(const float* v){
  uint4 o;
  o.x = (uint32_t)f2bf(v[0]) | ((uint32_t)f2bf(v[1])<<16);
  o.y = (uint32_t)f2bf(v[2]) | ((uint32_t)f2bf(v[3])<<16);
  o.z = (uint32_t)f2bf(v[4]) | ((uint32_t)f2bf(v[5])<<16);
  o.w = (uint32_t)f2bf(v[6]) | ((uint32_t)f2bf(v[7])<<16);
  return o;
}

// ---------------- misc small kernels ----------------

__global__ __launch_bounds__(256) void zero_k(int* deg, float* bnacc, int* bcnt){
  int i = blockIdx.x*256 + threadIdx.x;
  if (i < NN) deg[i] = 0;
  if (i < 3*8192) bnacc[i] = 0.f;
  if (i < NBK) bcnt[i] = 0;
}

__global__ __launch_bounds__(256) void cvt_k(const float* __restrict__ src, u16* __restrict__ dst, int n4){
  int i = blockIdx.x*256 + threadIdx.x;
  if (i >= n4) return;
  float4 v = ((const float4*)src)[i];
  uint2 o;
  o.x = (uint32_t)f2bf(v.x) | ((uint32_t)f2bf(v.y)<<16);
  o.y = (uint32_t)f2bf(v.z) | ((uint32_t)f2bf(v.w)<<16);
  ((uint2*)dst)[i] = o;
}

// pack W[K][NC] (f32 row-major) into MFMA B-fragment order:
// frag (ks, nt): lane l, elem j  <-  W[ks*32 + (l>>4)*8 + j][nt*16 + (l&15)]
__global__ __launch_bounds__(256) void pack_k(const float* __restrict__ src, u16* __restrict__ dst,
                                              int K, int NC, int ksoff){
  int t = blockIdx.x*256 + threadIdx.x;
  if (t >= K*NC) return;
  int k = t / NC, n = t % NC;
  int NT = NC >> 4;
  int ks = ksoff + (k >> 5);
  int l  = ((k >> 3) & 3)*16 + (n & 15);
  int j  = k & 7;
  dst[((size_t)(ks*NT + (n>>4))*64 + l)*8 + j] = f2bf(src[(size_t)k*NC + n]);
}

// ---------------- CSR build (bucketed) ----------------

__global__ __launch_bounds__(256) void deg_k(const int* __restrict__ ei, int* __restrict__ deg){
  int e = blockIdx.x*256 + threadIdx.x;
  if (e >= NE) return;
  atomicAdd(&deg[ei[NE + e]], 1);
}

__global__ __launch_bounds__(256) void bhist_k(const int* __restrict__ ei, int* __restrict__ bcnt){
  __shared__ int h[NBK];
  for (int i = threadIdx.x; i < NBK; i += 256) h[i] = 0;
  __syncthreads();
  int e0 = blockIdx.x * EPB;
  #pragma unroll
  for (int j = 0; j < EPB/256; ++j){
    int e = e0 + j*256 + threadIdx.x;
    if (e < NE) atomicAdd(&h[ei[NE + e] >> 8], 1);
  }
  __syncthreads();
  for (int i = threadIdx.x; i < NBK; i += 256)
    if (h[i]) atomicAdd(&bcnt[i], h[i]);
}

__global__ __launch_bounds__(512) void bscan_k(const int* __restrict__ bcnt, int* __restrict__ bcur){
  __shared__ int sd[512];
  int t = threadIdx.x;
  int v = (t < NBK) ? bcnt[t] : 0;
  sd[t] = v; __syncthreads();
  for (int o = 1; o < 512; o <<= 1){
    int x = (t >= o) ? sd[t-o] : 0;
    __syncthreads();
    sd[t] += x;
    __syncthreads();
  }
  if (t < NBK) bcur[t] = sd[t] - v;   // exclusive base, doubles as cursor
}

// per-block counting sort into bucket-grouped (src,dst) pairs
__global__ __launch_bounds__(256) void bfill_k(const int* __restrict__ ei, int* __restrict__ bcur,
                                               uint2* __restrict__ epair){
  __shared__ int cnt[NBK];
  __shared__ int gb[NBK];
  for (int i = threadIdx.x; i < NBK; i += 256) cnt[i] = 0;
  __syncthreads();
  int e0 = blockIdx.x * EPB;
  int srcv[EPB/256], dstv[EPB/256], rnk[EPB/256];
  #pragma unroll
  for (int j = 0; j < EPB/256; ++j){
    int e = e0 + j*256 + threadIdx.x;
    if (e < NE){
      srcv[j] = ei[e];
      dstv[j] = ei[NE + e];
      rnk[j]  = atomicAdd(&cnt[dstv[j] >> 8], 1);
    } else dstv[j] = -1;
  }
  __syncthreads();
  for (int i = threadIdx.x; i < NBK; i += 256){
    int c = cnt[i];
    gb[i] = c ? atomicAdd(&bcur[i], c) : 0;
  }
  __syncthreads();
  #pragma unroll
  for (int j = 0; j < EPB/256; ++j){
    if (dstv[j] >= 0)
      epair[gb[dstv[j] >> 8] + rnk[j]] = make_uint2((unsigned)srcv[j], (unsigned)dstv[j]);
  }
}

__global__ __launch_bounds__(256) void scan1_k(const int* __restrict__ deg, int* __restrict__ bsum){
  __shared__ int sd[256];
  int t = threadIdx.x, i = blockIdx.x*256 + t;
  sd[t] = (i < NN) ? deg[i] : 0;
  __syncthreads();
  for (int o = 128; o > 0; o >>= 1){ if (t < o) sd[t] += sd[t+o]; __syncthreads(); }
  if (t == 0) bsum[blockIdx.x] = sd[0];
}

__global__ __launch_bounds__(512) void scan2_k(const int* __restrict__ bsum, int* __restrict__ boff,
                                               int* __restrict__ rp, int NB){
  __shared__ int sd[512];
  int t = threadIdx.x;
  int v = (t < NB) ? bsum[t] : 0;
  sd[t] = v; __syncthreads();
  for (int o = 1; o < 512; o <<= 1){
    int x = (t >= o) ? sd[t-o] : 0;
    __syncthreads();
    sd[t] += x;
    __syncthreads();
  }
  if (t < NB) boff[t] = sd[t] - v;
  if (t == 511) rp[NN] = sd[511];
}

__global__ __launch_bounds__(256) void scan3_k(const int* __restrict__ deg, const int* __restrict__ boff,
                                               int* __restrict__ rp, int* __restrict__ cur){
  __shared__ int sd[256];
  int t = threadIdx.x, i = blockIdx.x*256 + t;
  int v = (i < NN) ? deg[i] : 0;
  sd[t] = v; __syncthreads();
  for (int o = 1; o < 256; o <<= 1){
    int x = (t >= o) ? sd[t-o] : 0;
    __syncthreads();
    sd[t] += x;
    __syncthreads();
  }
  if (i < NN){
    int ex = boff[blockIdx.x] + sd[t] - v;
    rp[i] = ex; cur[i] = ex;
  }
}

// final fill from bucket-grouped pairs: cur atomics + ci writes are L2-local
__global__ __launch_bounds__(256) void ffill_k(const uint2* __restrict__ epair, int* __restrict__ cur,
                                               int* __restrict__ ci){
  int e = blockIdx.x*256 + threadIdx.x;
  if (e >= NE) return;
  uint2 p = epair[e];
  int pos = atomicAdd(&cur[p.y], 1);
  ci[pos] = (int)p.x;
}

// ---------------- mean aggregation: one wave per node, 4-way MLP ----------------

__global__ __launch_bounds__(256) void agg_k(const int* __restrict__ rp, const int* __restrict__ ci,
                                             const u16* __restrict__ h, u16* __restrict__ ag){
  int w = (int)((blockIdx.x*256u + threadIdx.x) >> 6);
  int lane = threadIdx.x & 63;
  if (w >= NN) return;
  int e0 = rp[w], e1 = rp[w+1];
  const uint2* hu = (const uint2*)h;
  float a0=0.f, a1=0.f, a2=0.f, a3=0.f;
  for (int base = e0; base < e1; base += 64){
    int cnt = e1 - base; if (cnt > 64) cnt = 64;
    int my = ci[base + (lane < cnt ? lane : cnt-1)];
    int i = 0;
    for (; i + 4 <= cnt; i += 4){
      int s0 = __builtin_amdgcn_readlane(my, i);
      int s1 = __builtin_amdgcn_readlane(my, i+1);
      int s2 = __builtin_amdgcn_readlane(my, i+2);
      int s3 = __builtin_amdgcn_readlane(my, i+3);
      uint2 v0 = hu[(size_t)s0*64 + lane];
      uint2 v1 = hu[(size_t)s1*64 + lane];
      uint2 v2 = hu[(size_t)s2*64 + lane];
      uint2 v3 = hu[(size_t)s3*64 + lane];
      a0 += bf2f((u16)(v0.x&0xffffu)) + bf2f((u16)(v1.x&0xffffu)) + bf2f((u16)(v2.x&0xffffu)) + bf2f((u16)(v3.x&0xffffu));
      a1 += bf2f((u16)(v0.x>>16))     + bf2f((u16)(v1.x>>16))     + bf2f((u16)(v2.x>>16))     + bf2f((u16)(v3.x>>16));
      a2 += bf2f((u16)(v0.y&0xffffu)) + bf2f((u16)(v1.y&0xffffu)) + bf2f((u16)(v2.y&0xffffu)) + bf2f((u16)(v3.y&0xffffu));
      a3 += bf2f((u16)(v0.y>>16))     + bf2f((u16)(v1.y>>16))     + bf2f((u16)(v2.y>>16))     + bf2f((u16)(v3.y>>16));
    }
    for (; i < cnt; ++i){
      int s0 = __builtin_amdgcn_readlane(my, i);
      uint2 v = hu[(size_t)s0*64 + lane];
      a0 += bf2f((u16)(v.x&0xffffu));
      a1 += bf2f((u16)(v.x>>16));
      a2 += bf2f((u16)(v.y&0xffffu));
      a3 += bf2f((u16)(v.y>>16));
    }
  }
  int d = e1 - e0;
  float inv = 1.0f / (float)(d > 0 ? d : 1);
  uint2 o;
  o.x = (uint32_t)f2bf(a0*inv) | ((uint32_t)f2bf(a1*inv) << 16);
  o.y = (uint32_t)f2bf(a2*inv) | ((uint32_t)f2bf(a3*inv) << 16);
  ((uint2*)ag)[(size_t)w*64 + lane] = o;
}

// ---------------- MFMA GEMM: C[M,NC] = [A1|A2] @ Wpacked + bias ----------------
// block = 4 waves, 64 rows; wave covers NFRAG*16 cols.
// EPI 0: relu, store bf16.  EPI 1: store bf16 (no relu) + striped BN sum/sumsq atomics.

template<int NFRAG, int EPI>
__global__ __launch_bounds__(256) void gemm_k(
    const u16* __restrict__ A1, const u16* __restrict__ A2, int K1, int K2,
    const u16* __restrict__ Wp, const float* __restrict__ bias,
    u16* __restrict__ Cout, int NC, int M,
    float* __restrict__ stS, float* __restrict__ stQ)
{
  int lane = threadIdx.x & 63;
  int wv   = threadIdx.x >> 6;
  int rb   = blockIdx.x * 64;
  int col0 = wv * (NFRAG*16);
  int NT   = NC >> 4;
  int r15  = lane & 15, kg = lane >> 4;

  f32x4 acc[4][NFRAG];
  #pragma unroll
  for (int m = 0; m < 4; ++m)
    #pragma unroll
    for (int n = 0; n < NFRAG; ++n){ f32x4 z = {0.f,0.f,0.f,0.f}; acc[m][n] = z; }

  const int KS1 = K1 >> 5, KS2 = K2 >> 5;
  const u16* Bp = Wp + ((size_t)((col0 >> 4)*64 + lane))*8;
  const size_t bstep = (size_t)NT*64*8;

  const u16* A1base = A1 + (size_t)(rb + r15)*K1 + kg*8;
  for (int ks = 0; ks < KS1; ++ks){
    s16x8 a[4], b[NFRAG];
    const u16* Ab = A1base + ks*32;
    #pragma unroll
    for (int m = 0; m < 4; ++m) a[m] = *(const s16x8*)(Ab + (size_t)m*16*K1);
    const u16* Bb = Bp + (size_t)ks*bstep;
    #pragma unroll
    for (int n = 0; n < NFRAG; ++n) b[n] = *(const s16x8*)(Bb + (size_t)n*512);
    #pragma unroll
    for (int m = 0; m < 4; ++m)
      #pragma unroll
      for (int n = 0; n < NFRAG; ++n)
        acc[m][n] = __builtin_amdgcn_mfma_f32_16x16x32_bf16(a[m], b[n], acc[m][n], 0, 0, 0);
  }
  if (K2 > 0){
    const u16* A2base = A2 + (size_t)(rb + r15)*K2 + kg*8;
    for (int ks = 0; ks < KS2; ++ks){
      s16x8 a[4], b[NFRAG];
      const u16* Ab = A2base + ks*32;
      #pragma unroll
      for (int m = 0; m < 4; ++m) a[m] = *(const s16x8*)(Ab + (size_t)m*16*K2);
      const u16* Bb = Bp + (size_t)(KS1 + ks)*bstep;
      #pragma unroll
      for (int n = 0; n < NFRAG; ++n) b[n] = *(const s16x8*)(Bb + (size_t)n*512);
      #pragma unroll
      for (int m = 0; m < 4; ++m)
        #pragma unroll
        for (int n = 0; n < NFRAG; ++n)
          acc[m][n] = __builtin_amdgcn_mfma_f32_16x16x32_bf16(a[m], b[n], acc[m][n], 0, 0, 0);
    }
  }

  // Cout may alias A1 (out <- agg buffer): wait for ALL waves' reads first.
  __syncthreads();

  #pragma unroll
  for (int n = 0; n < NFRAG; ++n){
    int col = col0 + n*16 + r15;
    float bc = bias[col];
    float s = 0.f, q = 0.f;
    #pragma unroll
    for (int m = 0; m < 4; ++m){
      int rbase = rb + m*16 + kg*4;
      #pragma unroll
      for (int r = 0; r < 4; ++r){
        int row = rbase + r;
        float val = acc[m][n][r] + bc;
        if (EPI == 0) val = fmaxf(val, 0.f);
        bool ok = row < M;
        if (ok) Cout[(size_t)row*NC + col] = f2bf(val);
        if (EPI == 1 && ok){ s += val; q += val*val; }
      }
    }
    if (EPI == 1){
      s += __shfl_xor(s, 16); s += __shfl_xor(s, 32);
      q += __shfl_xor(q, 16); q += __shfl_xor(q, 32);
      if (lane < 16){
        int idx = col*16 + (blockIdx.x & 15);
        atomicAdd(&stS[idx], s);
        atomicAdd(&stQ[idx], q);
      }
    }
  }
}

// ---------------- BN finalize + apply ----------------

__global__ __launch_bounds__(256) void bnfin_k(const float* __restrict__ acc,
                                               const float* __restrict__ g, const float* __restrict__ b,
                                               float* __restrict__ coef){
  int c = threadIdx.x;
  float s = 0.f, q = 0.f;
  #pragma unroll
  for (int j = 0; j < 16; ++j){
    s += acc[c*16 + j];
    q += acc[4096 + c*16 + j];
  }
  float mean = s * (1.0f / (float)NN);
  float var  = q * (1.0f / (float)NN) - mean*mean;
  float sc = g[c] * rsqrtf(var + 1e-5f);
  coef[c] = sc;
  coef[256 + c] = b[c] - mean*sc;
}

__global__ __launch_bounds__(256) void bnapply_k(const uint4* __restrict__ outb, uint4* __restrict__ h,
                                                 const float* __restrict__ coef, int layer){
  int i = blockIdx.x*256 + threadIdx.x;
  if (i >= NN*32) return;
  int col0 = (i & 31) * 8;
  const float4* scp = (const float4*)(coef + col0);
  const float4* shp = (const float4*)(coef + 256 + col0);
  float4 s0 = scp[0], s1 = scp[1], t0 = shp[0], t1 = shp[1];
  float sc[8] = {s0.x,s0.y,s0.z,s0.w,s1.x,s1.y,s1.z,s1.w};
  float sh[8] = {t0.x,t0.y,t0.z,t0.w,t1.x,t1.y,t1.z,t1.w};
  float v[8], r[8];
  up8(outb[i], v);
  #pragma unroll
  for (int j = 0; j < 8; ++j) r[j] = fmaxf(v[j]*sc[j] + sh[j], 0.f);
  if (layer > 0){
    float hv[8];
    up8(h[i], hv);
    #pragma unroll
    for (int j = 0; j < 8; ++j) r[j] += hv[j];
  }
  h[i] = pk8(r);
}

// ---------------- fc2 logits + embeddings copy-out ----------------

__global__ __launch_bounds__(256) void fc2_k(const u16* __restrict__ z, const float* __restrict__ w2,
                                             const float* __restrict__ b2, float* __restrict__ out){
  int w = (int)((blockIdx.x*256u + threadIdx.x) >> 6);
  int lane = threadIdx.x & 63;
  if (w >= NN) return;
  const uint32_t* zu = (const uint32_t*)(z + (size_t)w*128);
  uint32_t p = zu[lane];
  float z0 = bf2f((u16)(p & 0xffffu));
  float z1 = bf2f((u16)(p >> 16));
  float4 wv = ((const float4*)w2)[lane];
  float p0 = z0*wv.x + z1*wv.z;
  float p1 = z0*wv.y + z1*wv.w;
  #pragma unroll
  for (int off = 1; off < 64; off <<= 1){
    p0 += __shfl_xor(p0, off);
    p1 += __shfl_xor(p1, off);
  }
  if (lane == 0){
    out[(size_t)w*2]     = p0 + b2[0];
    out[(size_t)w*2 + 1] = p1 + b2[1];
  }
}

__global__ __launch_bounds__(256) void emb_k(const u16* __restrict__ h, float* __restrict__ out, int n4){
  int i = blockIdx.x*256 + threadIdx.x;
  if (i >= n4) return;
  uint2 v = ((const uint2*)h)[i];
  float4 o;
  o.x = bf2f((u16)(v.x & 0xffffu));
  o.y = bf2f((u16)(v.x >> 16));
  o.z = bf2f((u16)(v.y & 0xffffu));
  o.w = bf2f((u16)(v.y >> 16));
  ((float4*)out)[i] = o;
}

// ---------------- host ----------------

extern "C" void kernel_launch(void* const* d_in, const int* in_sizes, int n_in,
                              void* d_out, int out_size, void* d_ws, size_t ws_size,
                              hipStream_t stream){
  const float* x       = (const float*)d_in[0];
  const int*   ei      = (const int*)d_in[1];
  const float* proj_w  = (const float*)d_in[2];
  const float* proj_b  = (const float*)d_in[3];
  const float* lin_l_w = (const float*)d_in[4];
  const float* lin_l_b = (const float*)d_in[5];
  const float* lin_r_w = (const float*)d_in[6];
  const float* bn_g    = (const float*)d_in[7];
  const float* bn_b    = (const float*)d_in[8];
  const float* fc1_w   = (const float*)d_in[9];
  const float* fc1_b   = (const float*)d_in[10];
  const float* fc2_w   = (const float*)d_in[11];
  const float* fc2_b   = (const float*)d_in[12];
  float* out = (float*)d_out;

  char* ws = (char*)d_ws;
  size_t off = 0;
  auto alloc = [&](size_t b){ size_t o = off; off = (off + b + 255) & ~(size_t)255; return o; };

  u16* bufA    = (u16*)(ws + alloc((size_t)MP*256*2));  // x_bf16 -> agg/out -> z
  u16* hbuf    = (u16*)(ws + alloc((size_t)MP*256*2));
  u16* wp_proj = (u16*)(ws + alloc((size_t)4*16*64*8*2));
  u16* wp_l[3];
  for (int i = 0; i < 3; ++i) wp_l[i] = (u16*)(ws + alloc((size_t)16*16*64*8*2));
  u16* wp_fc1  = (u16*)(ws + alloc((size_t)8*8*64*8*2));
  int* deg   = (int*)(ws + alloc((size_t)NN*4));
  int* cur   = (int*)(ws + alloc((size_t)NN*4));
  int* rp    = (int*)(ws + alloc((size_t)(NN+1)*4));
  int* ci    = (int*)(ws + alloc((size_t)NE*4));
  int* bsum  = (int*)(ws + alloc(512*4));
  int* boff  = (int*)(ws + alloc(512*4));
  int* bcnt  = (int*)(ws + alloc(NBK*4));
  int* bcur  = (int*)(ws + alloc(NBK*4));
  float* bnacc = (float*)(ws + alloc(3*8192*4));
  float* coef  = (float*)(ws + alloc(3*512*4));
  uint2* epair = (uint2*)hbuf;   // hbuf is dead until proj gemm
  (void)ws_size; (void)in_sizes; (void)n_in; (void)out_size;

  const int NB = (NN + 255)/256;  // 391
  const int BFB = (NE + EPB - 1)/EPB;  // 782

  zero_k<<<NB, 256, 0, stream>>>(deg, bnacc, bcnt);

  // CSR build (bucketed fill)
  deg_k<<<NE/256, 256, 0, stream>>>(ei, deg);
  bhist_k<<<BFB, 256, 0, stream>>>(ei, bcnt);
  bscan_k<<<1, 512, 0, stream>>>(bcnt, bcur);
  bfill_k<<<BFB, 256, 0, stream>>>(ei, bcur, epair);
  scan1_k<<<NB, 256, 0, stream>>>(deg, bsum);
  scan2_k<<<1, 512, 0, stream>>>(bsum, boff, rp, NB);
  scan3_k<<<NB, 256, 0, stream>>>(deg, boff, rp, cur);
  ffill_k<<<NE/256, 256, 0, stream>>>(epair, cur, ci);

  // weights + input cvt (after ffill: epair/hbuf alias is dead now)
  cvt_k<<<(NN*INC/4 + 255)/256, 256, 0, stream>>>(x, bufA, NN*INC/4);
  pack_k<<<(128*256 + 255)/256, 256, 0, stream>>>(proj_w, wp_proj, 128, 256, 0);
  for (int i = 0; i < 3; ++i){
    pack_k<<<(256*256 + 255)/256, 256, 0, stream>>>(lin_l_w + (size_t)i*65536, wp_l[i], 256, 256, 0);
    pack_k<<<(256*256 + 255)/256, 256, 0, stream>>>(lin_r_w + (size_t)i*65536, wp_l[i], 256, 256, 8);
  }
  pack_k<<<(256*128 + 255)/256, 256, 0, stream>>>(fc1_w, wp_fc1, 256, 128, 0);

  // proj: h = relu(x @ proj_w + proj_b)
  gemm_k<4,0><<<MBLK, 256, 0, stream>>>(bufA, nullptr, 128, 0, wp_proj, proj_b,
                                        hbuf, 256, NN, nullptr, nullptr);

  for (int i = 0; i < 3; ++i){
    agg_k<<<(NN + 3)/4, 256, 0, stream>>>(rp, ci, hbuf, bufA);
    gemm_k<4,1><<<MBLK, 256, 0, stream>>>(bufA, hbuf, 256, 256, wp_l[i], lin_l_b + (size_t)i*256,
                                          bufA, 256, NN, bnacc + i*8192, bnacc + i*8192 + 4096);
    bnfin_k<<<1, 256, 0, stream>>>(bnacc + i*8192, bn_g + (size_t)i*256, bn_b + (size_t)i*256, coef + i*512);
    bnapply_k<<<(NN*32 + 255)/256, 256, 0, stream>>>((const uint4*)bufA, (uint4*)hbuf, coef + i*512, i);
  }

  // fc1: z = relu(h @ fc1_w + fc1_b)
  gemm_k<2,0><<<MBLK, 256, 0, stream>>>(hbuf, nullptr, 256, 0, wp_fc1, fc1_b,
                                        bufA, 128, NN, nullptr, nullptr);
  fc2_k<<<(NN + 3)/4, 256, 0, stream>>>(bufA, fc2_w, fc2_b, out);
  emb_k<<<(NN*64 + 255)/256, 256, 0, stream>>>(hbuf, out + 200000, NN*64);
}

// Round 3
// 1085.733 us; speedup vs baseline: 1.0987x; 1.0987x over previous
//
#include <hip/hip_runtime.h>
#include <stdint.h>

#define NN 100000      // nodes
#define NE 1600000     // edges
#define INC 128        // in channels
#define HID 256        // hidden
#define MP  100032     // padded rows (64*1563)
#define MBLK 1563      // row blocks of 64
#define NBK 391        // dst buckets (dst>>8), 99999>>8 = 390
#define EPB 2048       // edges per bucket-fill block

typedef unsigned short u16;
typedef __attribute__((ext_vector_type(4))) float f32x4;
typedef __attribute__((ext_vector_type(8))) short s16x8;

static __device__ __forceinline__ float bf2f(u16 u){
  union { uint32_t i; float f; } v; v.i = ((uint32_t)u) << 16; return v.f;
}
static __device__ __forceinline__ u16 f2bf(float f){
  union { float f; uint32_t i; } v; v.f = f;
  uint32_t r = v.i + 0x7FFFu + ((v.i >> 16) & 1u);
  return (u16)(r >> 16);
}
static __device__ __forceinline__ void up8(uint4 o, float* v){
  v[0]=bf2f((u16)(o.x&0xffffu)); v[1]=bf2f((u16)(o.x>>16));
  v[2]=bf2f((u16)(o.y&0xffffu)); v[3]=bf2f((u16)(o.y>>16));
  v[4]=bf2f((u16)(o.z&0xffffu)); v[5]=bf2f((u16)(o.z>>16));
  v[6]=bf2f((u16)(o.w&0xffffu)); v[7]=bf2f((u16)(o.w>>16));
}
static __device__ __forceinline__ uint4 pk8(const float* v){
  uint4 o;
  o.x = (uint32_t)f2bf(v[0]) | ((uint32_t)f2bf(v[1])<<16);
  o.y = (uint32_t)f2bf(v[2]) | ((uint32_t)f2bf(v[3])<<16);
  o.z = (uint32_t)f2bf(v[4]) | ((uint32_t)f2bf(v[5])<<16);
  o.w = (uint32_t)f2bf(v[6]) | ((uint32_t)f2bf(v[7])<<16);
  return o;
}

// ---------------- misc small kernels ----------------

__global__ __launch_bounds__(256) void zero_k(int* deg, float* bnacc, int* bcnt){
  int i = blockIdx.x*256 + threadIdx.x;
  if (i < NN) deg[i] = 0;
  if (i < 3*512) bnacc[i] = 0.f;
  if (i < NBK) bcnt[i] = 0;
}

__global__ __launch_bounds__(256) void cvt_k(const float* __restrict__ src, u16* __restrict__ dst, int n4){
  int i = blockIdx.x*256 + threadIdx.x;
  if (i >= n4) return;
  float4 v = ((const float4*)src)[i];
  uint2 o;
  o.x = (uint32_t)f2bf(v.x) | ((uint32_t)f2bf(v.y)<<16);
  o.y = (uint32_t)f2bf(v.z) | ((uint32_t)f2bf(v.w)<<16);
  ((uint2*)dst)[i] = o;
}

// pack W[K][NC] (f32 row-major) into MFMA B-fragment order:
// frag (ks, nt): lane l, elem j  <-  W[ks*32 + (l>>4)*8 + j][nt*16 + (l&15)]
__global__ __launch_bounds__(256) void pack_k(const float* __restrict__ src, u16* __restrict__ dst,
                                              int K, int NC, int ksoff){
  int t = blockIdx.x*256 + threadIdx.x;
  if (t >= K*NC) return;
  int k = t / NC, n = t % NC;
  int NT = NC >> 4;
  int ks = ksoff + (k >> 5);
  int l  = ((k >> 3) & 3)*16 + (n & 15);
  int j  = k & 7;
  dst[((size_t)(ks*NT + (n>>4))*64 + l)*8 + j] = f2bf(src[(size_t)k*NC + n]);
}

// ---------------- CSR build (bucketed) ----------------

__global__ __launch_bounds__(256) void deg_k(const int* __restrict__ ei, int* __restrict__ deg){
  int e = blockIdx.x*256 + threadIdx.x;
  if (e >= NE) return;
  atomicAdd(&deg[ei[NE + e]], 1);
}

__global__ __launch_bounds__(256) void bhist_k(const int* __restrict__ ei, int* __restrict__ bcnt){
  __shared__ int h[NBK];
  for (int i = threadIdx.x; i < NBK; i += 256) h[i] = 0;
  __syncthreads();
  int e0 = blockIdx.x * EPB;
  #pragma unroll
  for (int j = 0; j < EPB/256; ++j){
    int e = e0 + j*256 + threadIdx.x;
    if (e < NE) atomicAdd(&h[ei[NE + e] >> 8], 1);
  }
  __syncthreads();
  for (int i = threadIdx.x; i < NBK; i += 256)
    if (h[i]) atomicAdd(&bcnt[i], h[i]);
}

__global__ __launch_bounds__(512) void bscan_k(const int* __restrict__ bcnt, int* __restrict__ bcur){
  __shared__ int sd[512];
  int t = threadIdx.x;
  int v = (t < NBK) ? bcnt[t] : 0;
  sd[t] = v; __syncthreads();
  for (int o = 1; o < 512; o <<= 1){
    int x = (t >= o) ? sd[t-o] : 0;
    __syncthreads();
    sd[t] += x;
    __syncthreads();
  }
  if (t < NBK) bcur[t] = sd[t] - v;   // exclusive base, doubles as cursor
}

// per-block counting sort into bucket-grouped (src,dst) pairs
__global__ __launch_bounds__(256) void bfill_k(const int* __restrict__ ei, int* __restrict__ bcur,
                                               uint2* __restrict__ epair){
  __shared__ int cnt[NBK];
  __shared__ int gb[NBK];
  for (int i = threadIdx.x; i < NBK; i += 256) cnt[i] = 0;
  __syncthreads();
  int e0 = blockIdx.x * EPB;
  int srcv[EPB/256], dstv[EPB/256], rnk[EPB/256];
  #pragma unroll
  for (int j = 0; j < EPB/256; ++j){
    int e = e0 + j*256 + threadIdx.x;
    if (e < NE){
      srcv[j] = ei[e];
      dstv[j] = ei[NE + e];
      rnk[j]  = atomicAdd(&cnt[dstv[j] >> 8], 1);
    } else dstv[j] = -1;
  }
  __syncthreads();
  for (int i = threadIdx.x; i < NBK; i += 256){
    int c = cnt[i];
    gb[i] = c ? atomicAdd(&bcur[i], c) : 0;
  }
  __syncthreads();
  #pragma unroll
  for (int j = 0; j < EPB/256; ++j){
    if (dstv[j] >= 0)
      epair[gb[dstv[j] >> 8] + rnk[j]] = make_uint2((unsigned)srcv[j], (unsigned)dstv[j]);
  }
}

__global__ __launch_bounds__(256) void scan1_k(const int* __restrict__ deg, int* __restrict__ bsum){
  __shared__ int sd[256];
  int t = threadIdx.x, i = blockIdx.x*256 + t;
  sd[t] = (i < NN) ? deg[i] : 0;
  __syncthreads();
  for (int o = 128; o > 0; o >>= 1){ if (t < o) sd[t] += sd[t+o]; __syncthreads(); }
  if (t == 0) bsum[blockIdx.x] = sd[0];
}

__global__ __launch_bounds__(512) void scan2_k(const int* __restrict__ bsum, int* __restrict__ boff,
                                               int* __restrict__ rp, int NB){
  __shared__ int sd[512];
  int t = threadIdx.x;
  int v = (t < NB) ? bsum[t] : 0;
  sd[t] = v; __syncthreads();
  for (int o = 1; o < 512; o <<= 1){
    int x = (t >= o) ? sd[t-o] : 0;
    __syncthreads();
    sd[t] += x;
    __syncthreads();
  }
  if (t < NB) boff[t] = sd[t] - v;
  if (t == 511) rp[NN] = sd[511];
}

__global__ __launch_bounds__(256) void scan3_k(const int* __restrict__ deg, const int* __restrict__ boff,
                                               int* __restrict__ rp, int* __restrict__ cur){
  __shared__ int sd[256];
  int t = threadIdx.x, i = blockIdx.x*256 + t;
  int v = (i < NN) ? deg[i] : 0;
  sd[t] = v; __syncthreads();
  for (int o = 1; o < 256; o <<= 1){
    int x = (t >= o) ? sd[t-o] : 0;
    __syncthreads();
    sd[t] += x;
    __syncthreads();
  }
  if (i < NN){
    int ex = boff[blockIdx.x] + sd[t] - v;
    rp[i] = ex; cur[i] = ex;
  }
}

// final fill from bucket-grouped pairs: cur atomics + ci writes are L2-local
__global__ __launch_bounds__(256) void ffill_k(const uint2* __restrict__ epair, int* __restrict__ cur,
                                               int* __restrict__ ci){
  int e = blockIdx.x*256 + threadIdx.x;
  if (e >= NE) return;
  uint2 p = epair[e];
  int pos = atomicAdd(&cur[p.y], 1);
  ci[pos] = (int)p.x;
}

// ---------------- mean aggregation: one wave per node, 4-way MLP ----------------

__global__ __launch_bounds__(256) void agg_k(const int* __restrict__ rp, const int* __restrict__ ci,
                                             const u16* __restrict__ h, u16* __restrict__ ag){
  int w = (int)((blockIdx.x*256u + threadIdx.x) >> 6);
  int lane = threadIdx.x & 63;
  if (w >= NN) return;
  int e0 = rp[w], e1 = rp[w+1];
  const uint2* hu = (const uint2*)h;
  float a0=0.f, a1=0.f, a2=0.f, a3=0.f;
  for (int base = e0; base < e1; base += 64){
    int cnt = e1 - base; if (cnt > 64) cnt = 64;
    int my = ci[base + (lane < cnt ? lane : cnt-1)];
    int i = 0;
    for (; i + 4 <= cnt; i += 4){
      int s0 = __builtin_amdgcn_readlane(my, i);
      int s1 = __builtin_amdgcn_readlane(my, i+1);
      int s2 = __builtin_amdgcn_readlane(my, i+2);
      int s3 = __builtin_amdgcn_readlane(my, i+3);
      uint2 v0 = hu[(size_t)s0*64 + lane];
      uint2 v1 = hu[(size_t)s1*64 + lane];
      uint2 v2 = hu[(size_t)s2*64 + lane];
      uint2 v3 = hu[(size_t)s3*64 + lane];
      a0 += bf2f((u16)(v0.x&0xffffu)) + bf2f((u16)(v1.x&0xffffu)) + bf2f((u16)(v2.x&0xffffu)) + bf2f((u16)(v3.x&0xffffu));
      a1 += bf2f((u16)(v0.x>>16))     + bf2f((u16)(v1.x>>16))     + bf2f((u16)(v2.x>>16))     + bf2f((u16)(v3.x>>16));
      a2 += bf2f((u16)(v0.y&0xffffu)) + bf2f((u16)(v1.y&0xffffu)) + bf2f((u16)(v2.y&0xffffu)) + bf2f((u16)(v3.y&0xffffu));
      a3 += bf2f((u16)(v0.y>>16))     + bf2f((u16)(v1.y>>16))     + bf2f((u16)(v2.y>>16))     + bf2f((u16)(v3.y>>16));
    }
    for (; i < cnt; ++i){
      int s0 = __builtin_amdgcn_readlane(my, i);
      uint2 v = hu[(size_t)s0*64 + lane];
      a0 += bf2f((u16)(v.x&0xffffu));
      a1 += bf2f((u16)(v.x>>16));
      a2 += bf2f((u16)(v.y&0xffffu));
      a3 += bf2f((u16)(v.y>>16));
    }
  }
  int d = e1 - e0;
  float inv = 1.0f / (float)(d > 0 ? d : 1);
  uint2 o;
  o.x = (uint32_t)f2bf(a0*inv) | ((uint32_t)f2bf(a1*inv) << 16);
  o.y = (uint32_t)f2bf(a2*inv) | ((uint32_t)f2bf(a3*inv) << 16);
  ((uint2*)ag)[(size_t)w*64 + lane] = o;
}

// ---------------- MFMA GEMM: C[M,NC] = [A1|A2] @ Wpacked + bias ----------------
// block = 4 waves, 64 rows; wave covers NFRAG*16 cols. K-loop fully unrolled
// (KS1/KS2 compile-time) with depth-1 register double-buffer prefetch.
// EPI 0: relu, store bf16.  EPI 1: store bf16 (no relu) + BN sum/sumsq atomics.

template<int NFRAG, int EPI, int KS1, int KS2>
__global__ __launch_bounds__(256) void gemm_k(
    const u16* __restrict__ A1, const u16* __restrict__ A2,
    const u16* __restrict__ Wp, const float* __restrict__ bias,
    u16* __restrict__ Cout, int M,
    float* __restrict__ stS, float* __restrict__ stQ)
{
  constexpr int NC  = NFRAG*64;
  constexpr int NT  = NC >> 4;
  constexpr int K1  = KS1*32;
  constexpr int K2  = KS2*32;
  constexpr int KST = KS1 + KS2;

  int lane = threadIdx.x & 63;
  int wv   = threadIdx.x >> 6;
  int rb   = blockIdx.x * 64;
  int col0 = wv * (NFRAG*16);
  int r15  = lane & 15, kg = lane >> 4;

  f32x4 acc[4][NFRAG];
  #pragma unroll
  for (int m = 0; m < 4; ++m)
    #pragma unroll
    for (int n = 0; n < NFRAG; ++n){ f32x4 z = {0.f,0.f,0.f,0.f}; acc[m][n] = z; }

  const u16* Bp = Wp + ((size_t)((col0 >> 4)*64 + lane))*8;
  constexpr size_t bstep = (size_t)NT*64*8;

  const u16* A1base = A1 + (size_t)(rb + r15)*K1 + kg*8;
  const u16* A2base = (KS2 > 0) ? (A2 + (size_t)(rb + r15)*K2 + kg*8) : A1base;

  s16x8 abuf[2][4], bbuf[2][NFRAG];

  // prologue: load ks=0
  #pragma unroll
  for (int m = 0; m < 4; ++m) abuf[0][m] = *(const s16x8*)(A1base + (size_t)m*16*K1);
  #pragma unroll
  for (int n = 0; n < NFRAG; ++n) bbuf[0][n] = *(const s16x8*)(Bp + (size_t)n*512);

  #pragma unroll
  for (int ks = 0; ks < KST; ++ks){
    const int cur = ks & 1, nxt = cur ^ 1;
    if (ks + 1 < KST){
      const int ksn = ks + 1;
      if (ksn < KS1){
        const u16* Ab = A1base + ksn*32;
        #pragma unroll
        for (int m = 0; m < 4; ++m) abuf[nxt][m] = *(const s16x8*)(Ab + (size_t)m*16*K1);
      } else {
        const u16* Ab = A2base + (ksn - KS1)*32;
        #pragma unroll
        for (int m = 0; m < 4; ++m) abuf[nxt][m] = *(const s16x8*)(Ab + (size_t)m*16*K2);
      }
      const u16* Bb = Bp + (size_t)ksn*bstep;
      #pragma unroll
      for (int n = 0; n < NFRAG; ++n) bbuf[nxt][n] = *(const s16x8*)(Bb + (size_t)n*512);
    }
    #pragma unroll
    for (int m = 0; m < 4; ++m)
      #pragma unroll
      for (int n = 0; n < NFRAG; ++n)
        acc[m][n] = __builtin_amdgcn_mfma_f32_16x16x32_bf16(abuf[cur][m], bbuf[cur][n], acc[m][n], 0, 0, 0);
  }

  // Cout may alias A1 (out <- agg buffer): wait for ALL waves' reads first.
  __syncthreads();

  #pragma unroll
  for (int n = 0; n < NFRAG; ++n){
    int col = col0 + n*16 + r15;
    float bc = bias[col];
    float s = 0.f, q = 0.f;
    #pragma unroll
    for (int m = 0; m < 4; ++m){
      int rbase = rb + m*16 + kg*4;
      #pragma unroll
      for (int r = 0; r < 4; ++r){
        int row = rbase + r;
        float val = acc[m][n][r] + bc;
        if (EPI == 0) val = fmaxf(val, 0.f);
        bool ok = row < M;
        if (ok) Cout[(size_t)row*NC + col] = f2bf(val);
        if (EPI == 1 && ok){ s += val; q += val*val; }
      }
    }
    if (EPI == 1){
      s += __shfl_xor(s, 16); s += __shfl_xor(s, 32);
      q += __shfl_xor(q, 16); q += __shfl_xor(q, 32);
      if (lane < 16){
        atomicAdd(&stS[col], s);
        atomicAdd(&stQ[col], q);
      }
    }
  }
}

// ---------------- BN finalize + apply ----------------

__global__ __launch_bounds__(256) void bnfin_k(const float* __restrict__ acc,
                                               const float* __restrict__ g, const float* __restrict__ b,
                                               float* __restrict__ coef){
  int c = threadIdx.x;
  float s = acc[c], q = acc[256 + c];
  float mean = s * (1.0f / (float)NN);
  float var  = q * (1.0f / (float)NN) - mean*mean;
  float sc = g[c] * rsqrtf(var + 1e-5f);
  coef[c] = sc;
  coef[256 + c] = b[c] - mean*sc;
}

__global__ __launch_bounds__(256) void bnapply_k(const uint4* __restrict__ outb, uint4* __restrict__ h,
                                                 const float* __restrict__ coef, int layer){
  int i = blockIdx.x*256 + threadIdx.x;
  if (i >= NN*32) return;
  int col0 = (i & 31) * 8;
  const float4* scp = (const float4*)(coef + col0);
  const float4* shp = (const float4*)(coef + 256 + col0);
  float4 s0 = scp[0], s1 = scp[1], t0 = shp[0], t1 = shp[1];
  float sc[8] = {s0.x,s0.y,s0.z,s0.w,s1.x,s1.y,s1.z,s1.w};
  float sh[8] = {t0.x,t0.y,t0.z,t0.w,t1.x,t1.y,t1.z,t1.w};
  float v[8], r[8];
  up8(outb[i], v);
  #pragma unroll
  for (int j = 0; j < 8; ++j) r[j] = fmaxf(v[j]*sc[j] + sh[j], 0.f);
  if (layer > 0){
    float hv[8];
    up8(h[i], hv);
    #pragma unroll
    for (int j = 0; j < 8; ++j) r[j] += hv[j];
  }
  h[i] = pk8(r);
}

// ---------------- fc2 logits + embeddings copy-out ----------------

__global__ __launch_bounds__(256) void fc2_k(const u16* __restrict__ z, const float* __restrict__ w2,
                                             const float* __restrict__ b2, float* __restrict__ out){
  int w = (int)((blockIdx.x*256u + threadIdx.x) >> 6);
  int lane = threadIdx.x & 63;
  if (w >= NN) return;
  const uint32_t* zu = (const uint32_t*)(z + (size_t)w*128);
  uint32_t p = zu[lane];
  float z0 = bf2f((u16)(p & 0xffffu));
  float z1 = bf2f((u16)(p >> 16));
  float4 wv = ((const float4*)w2)[lane];
  float p0 = z0*wv.x + z1*wv.z;
  float p1 = z0*wv.y + z1*wv.w;
  #pragma unroll
  for (int off = 1; off < 64; off <<= 1){
    p0 += __shfl_xor(p0, off);
    p1 += __shfl_xor(p1, off);
  }
  if (lane == 0){
    out[(size_t)w*2]     = p0 + b2[0];
    out[(size_t)w*2 + 1] = p1 + b2[1];
  }
}

__global__ __launch_bounds__(256) void emb_k(const u16* __restrict__ h, float* __restrict__ out, int n4){
  int i = blockIdx.x*256 + threadIdx.x;
  if (i >= n4) return;
  uint2 v = ((const uint2*)h)[i];
  float4 o;
  o.x = bf2f((u16)(v.x & 0xffffu));
  o.y = bf2f((u16)(v.x >> 16));
  o.z = bf2f((u16)(v.y & 0xffffu));
  o.w = bf2f((u16)(v.y >> 16));
  ((float4*)out)[i] = o;
}

// ---------------- host ----------------

extern "C" void kernel_launch(void* const* d_in, const int* in_sizes, int n_in,
                              void* d_out, int out_size, void* d_ws, size_t ws_size,
                              hipStream_t stream){
  const float* x       = (const float*)d_in[0];
  const int*   ei      = (const int*)d_in[1];
  const float* proj_w  = (const float*)d_in[2];
  const float* proj_b  = (const float*)d_in[3];
  const float* lin_l_w = (const float*)d_in[4];
  const float* lin_l_b = (const float*)d_in[5];
  const float* lin_r_w = (const float*)d_in[6];
  const float* bn_g    = (const float*)d_in[7];
  const float* bn_b    = (const float*)d_in[8];
  const float* fc1_w   = (const float*)d_in[9];
  const float* fc1_b   = (const float*)d_in[10];
  const float* fc2_w   = (const float*)d_in[11];
  const float* fc2_b   = (const float*)d_in[12];
  float* out = (float*)d_out;

  char* ws = (char*)d_ws;
  size_t off = 0;
  auto alloc = [&](size_t b){ size_t o = off; off = (off + b + 255) & ~(size_t)255; return o; };

  u16* bufA    = (u16*)(ws + alloc((size_t)MP*256*2));  // x_bf16 -> agg/out -> z
  u16* hbuf    = (u16*)(ws + alloc((size_t)MP*256*2));
  u16* wp_proj = (u16*)(ws + alloc((size_t)4*16*64*8*2));
  u16* wp_l[3];
  for (int i = 0; i < 3; ++i) wp_l[i] = (u16*)(ws + alloc((size_t)16*16*64*8*2));
  u16* wp_fc1  = (u16*)(ws + alloc((size_t)8*8*64*8*2));
  int* deg   = (int*)(ws + alloc((size_t)NN*4));
  int* cur   = (int*)(ws + alloc((size_t)NN*4));
  int* rp    = (int*)(ws + alloc((size_t)(NN+1)*4));
  int* ci    = (int*)(ws + alloc((size_t)NE*4));
  int* bsum  = (int*)(ws + alloc(512*4));
  int* boff  = (int*)(ws + alloc(512*4));
  int* bcnt  = (int*)(ws + alloc(NBK*4));
  int* bcur  = (int*)(ws + alloc(NBK*4));
  float* bnacc = (float*)(ws + alloc(3*512*4));
  float* coef  = (float*)(ws + alloc(3*512*4));
  uint2* epair = (uint2*)hbuf;   // hbuf is dead until proj gemm
  (void)ws_size; (void)in_sizes; (void)n_in; (void)out_size;

  const int NB = (NN + 255)/256;  // 391
  const int BFB = (NE + EPB - 1)/EPB;  // 782

  zero_k<<<NB, 256, 0, stream>>>(deg, bnacc, bcnt);

  // CSR build (bucketed fill)
  deg_k<<<NE/256, 256, 0, stream>>>(ei, deg);
  bhist_k<<<BFB, 256, 0, stream>>>(ei, bcnt);
  bscan_k<<<1, 512, 0, stream>>>(bcnt, bcur);
  bfill_k<<<BFB, 256, 0, stream>>>(ei, bcur, epair);
  scan1_k<<<NB, 256, 0, stream>>>(deg, bsum);
  scan2_k<<<1, 512, 0, stream>>>(bsum, boff, rp, NB);
  scan3_k<<<NB, 256, 0, stream>>>(deg, boff, rp, cur);
  ffill_k<<<NE/256, 256, 0, stream>>>(epair, cur, ci);

  // weights + input cvt (after ffill: epair/hbuf alias is dead now)
  cvt_k<<<(NN*INC/4 + 255)/256, 256, 0, stream>>>(x, bufA, NN*INC/4);
  pack_k<<<(128*256 + 255)/256, 256, 0, stream>>>(proj_w, wp_proj, 128, 256, 0);
  for (int i = 0; i < 3; ++i){
    pack_k<<<(256*256 + 255)/256, 256, 0, stream>>>(lin_l_w + (size_t)i*65536, wp_l[i], 256, 256, 0);
    pack_k<<<(256*256 + 255)/256, 256, 0, stream>>>(lin_r_w + (size_t)i*65536, wp_l[i], 256, 256, 8);
  }
  pack_k<<<(256*128 + 255)/256, 256, 0, stream>>>(fc1_w, wp_fc1, 256, 128, 0);

  // proj: h = relu(x @ proj_w + proj_b)
  gemm_k<4,0,4,0><<<MBLK, 256, 0, stream>>>(bufA, nullptr, wp_proj, proj_b,
                                            hbuf, NN, nullptr, nullptr);

  for (int i = 0; i < 3; ++i){
    agg_k<<<(NN + 3)/4, 256, 0, stream>>>(rp, ci, hbuf, bufA);
    gemm_k<4,1,8,8><<<MBLK, 256, 0, stream>>>(bufA, hbuf, wp_l[i], lin_l_b + (size_t)i*256,
                                              bufA, NN, bnacc + i*512, bnacc + i*512 + 256);
    bnfin_k<<<1, 256, 0, stream>>>(bnacc + i*512, bn_g + (size_t)i*256, bn_b + (size_t)i*256, coef + i*512);
    bnapply_k<<<(NN*32 + 255)/256, 256, 0, stream>>>((const uint4*)bufA, (uint4*)hbuf, coef + i*512, i);
  }

  // fc1: z = relu(h @ fc1_w + fc1_b)
  gemm_k<2,0,8,0><<<MBLK, 256, 0, stream>>>(hbuf, nullptr, wp_fc1, fc1_b,
                                            bufA, NN, nullptr, nullptr);
  fc2_k<<<(NN + 3)/4, 256, 0, stream>>>(bufA, fc2_w, fc2_b, out);
  emb_k<<<(NN*64 + 255)/256, 256, 0, stream>>>(hbuf, out + 200000, NN*64);
}